// Round 1
// baseline (240.033 us; speedup 1.0000x reference)
//
#include <hip/hip_runtime.h>
#include <math.h>

// ContentAttention fused kernel for MI355X (gfx950).
// S = Q·K^T via bf16 hi/lo 3-product MFMA (fp32-grade accuracy), fused masked
// softmax + logsumexp->sigmoid confidence. No workspace used.
//
// Shapes: B=32, Q=512, K=512, D=1024 (fp32 in, fp32 out).
// Out layout: attn (B,Q,K) flat, then confidence (B,Q).

#define NB 32
#define NQ 512
#define NK 512
#define ND 1024
#define BM 64      // q-rows per block
#define BK 32      // D-tile depth
#define WCOLS 128  // key-cols per wave (4 waves cover NK=512)

typedef __attribute__((ext_vector_type(8))) short short8;
typedef __attribute__((ext_vector_type(4))) float f32x4;

// Split fp32 x into bf16 hi (round-to-nearest bits<<16) and fp32 residual lo.
__device__ __forceinline__ void bf_split(float x, unsigned& hbits, float& lo) {
  unsigned u = __float_as_uint(x);
  unsigned r = u + 0x7fffu + ((u >> 16) & 1u);
  hbits = r & 0xffff0000u;              // hi value as float bits
  lo = x - __uint_as_float(hbits);      // exact residual
}

// Pack two floats as round-to-nearest bf16 pair (x1 in high half).
__device__ __forceinline__ unsigned pack_rn(float x0, float x1) {
  unsigned u0 = __float_as_uint(x0), u1 = __float_as_uint(x1);
  unsigned r0 = u0 + 0x7fffu + ((u0 >> 16) & 1u);
  unsigned r1 = u1 + 0x7fffu + ((u1 >> 16) & 1u);
  return (r0 >> 16) | (r1 & 0xffff0000u);
}

// LDS layout: row-major, 32 bf16 (64B) per row; the four 16B chunks of each
// row are rotated by (row>>1) so a 16-lane frag read (rows n..n+15, fixed
// chunk) spreads 2-way over all 8 bank groups (2-way is free, m136).
__device__ __forceinline__ int lds_off_write(int r, int c4) {
  int slot = ((c4 >> 1) + (r >> 1)) & 3;
  return r * 32 + slot * 8 + (c4 & 1) * 4;   // ushort units
}
__device__ __forceinline__ int lds_off_read(int r, int quad) {
  int slot = (quad + (r >> 1)) & 3;
  return r * 32 + slot * 8;                  // ushort units (16B frag)
}

__global__ __launch_bounds__(256, 1)
void attn_fused(const float* __restrict__ Qg, const float* __restrict__ Kg,
                const float* __restrict__ Tp, const float* __restrict__ Bp,
                float* __restrict__ attn, float* __restrict__ conf) {
  __shared__ __align__(16) unsigned short sAhi[BM * BK];
  __shared__ __align__(16) unsigned short sAlo[BM * BK];
  __shared__ __align__(16) unsigned short sBhi[NK * BK];
  __shared__ __align__(16) unsigned short sBlo[NK * BK];
  __shared__ float sRedA[4][BM];
  __shared__ float sRedB[4][BM];

  const int tid = threadIdx.x;
  const int g = blockIdx.x;
  // XCD-aware: all 8 q-tile blocks of a batch share one XCD (round-robin % 8)
  const int batch = (g & 7) | (((g >> 3) & 3) << 3);
  const int q0 = (g >> 5) * BM;
  const int ln = tid & 63, w = tid >> 6;
  const int ln15 = ln & 15, quad = ln >> 4;
  const int wn0 = w * WCOLS;

  const float* Qp = Qg + ((size_t)batch * NQ + q0) * ND;
  const float* Kp = Kg + (size_t)batch * NK * ND;

  f32x4 acc[4][8];
#pragma unroll
  for (int mt = 0; mt < 4; ++mt)
#pragma unroll
    for (int nt = 0; nt < 8; ++nt)
      acc[mt][nt] = (f32x4){0.f, 0.f, 0.f, 0.f};

  // ---- register prefetch of tile 0 ----
  float4 pb[16];
  float4 pa[2];
#pragma unroll
  for (int i = 0; i < 16; ++i) {
    int idx = tid + 256 * i;
    int r = idx >> 3, c4 = idx & 7;
    pb[i] = *(const float4*)(Kp + (size_t)r * ND + c4 * 4);
  }
#pragma unroll
  for (int i = 0; i < 2; ++i) {
    int idx = tid + 256 * i;
    int r = idx >> 3, c4 = idx & 7;
    pa[i] = *(const float4*)(Qp + (size_t)r * ND + c4 * 4);
  }

  for (int kt = 0; kt < ND / BK; ++kt) {
    if (kt) __syncthreads();  // prior tile's frag reads done before overwrite

    // ---- convert prefetched fp32 -> bf16 hi/lo into LDS ----
#pragma unroll
    for (int i = 0; i < 2; ++i) {
      int idx = tid + 256 * i;
      int r = idx >> 3, c4 = idx & 7;
      int off = lds_off_write(r, c4);
      float4 v = pa[i];
      unsigned h0, h1, h2, h3;
      float l0, l1, l2, l3;
      bf_split(v.x, h0, l0); bf_split(v.y, h1, l1);
      bf_split(v.z, h2, l2); bf_split(v.w, h3, l3);
      *(uint2*)(&sAhi[off]) = make_uint2((h0 >> 16) | h1, (h2 >> 16) | h3);
      *(uint2*)(&sAlo[off]) = make_uint2(pack_rn(l0, l1), pack_rn(l2, l3));
    }
#pragma unroll
    for (int i = 0; i < 16; ++i) {
      int idx = tid + 256 * i;
      int r = idx >> 3, c4 = idx & 7;
      int off = lds_off_write(r, c4);
      float4 v = pb[i];
      unsigned h0, h1, h2, h3;
      float l0, l1, l2, l3;
      bf_split(v.x, h0, l0); bf_split(v.y, h1, l1);
      bf_split(v.z, h2, l2); bf_split(v.w, h3, l3);
      *(uint2*)(&sBhi[off]) = make_uint2((h0 >> 16) | h1, (h2 >> 16) | h3);
      *(uint2*)(&sBlo[off]) = make_uint2(pack_rn(l0, l1), pack_rn(l2, l3));
    }
    __syncthreads();

    // ---- prefetch next tile (latency hides behind MFMA below) ----
    if (kt < ND / BK - 1) {
      const float* Kq = Kp + (kt + 1) * BK;
      const float* Qq = Qp + (kt + 1) * BK;
#pragma unroll
      for (int i = 0; i < 16; ++i) {
        int idx = tid + 256 * i;
        int r = idx >> 3, c4 = idx & 7;
        pb[i] = *(const float4*)(Kq + (size_t)r * ND + c4 * 4);
      }
#pragma unroll
      for (int i = 0; i < 2; ++i) {
        int idx = tid + 256 * i;
        int r = idx >> 3, c4 = idx & 7;
        pa[i] = *(const float4*)(Qq + (size_t)r * ND + c4 * 4);
      }
    }

    // ---- MFMA: 3-product hi/lo per (mt,nt) ----
    short8 ahi[4], alo[4];
#pragma unroll
    for (int mt = 0; mt < 4; ++mt) {
      int r = mt * 16 + ln15;
      int off = lds_off_read(r, quad);
      ahi[mt] = *(const short8*)(&sAhi[off]);
      alo[mt] = *(const short8*)(&sAlo[off]);
    }
#pragma unroll
    for (int nt = 0; nt < 8; ++nt) {
      int r = wn0 + nt * 16 + ln15;
      int off = lds_off_read(r, quad);
      short8 bhi = *(const short8*)(&sBhi[off]);
      short8 blo = *(const short8*)(&sBlo[off]);
#pragma unroll
      for (int mt = 0; mt < 4; ++mt) {
        acc[mt][nt] = __builtin_amdgcn_mfma_f32_16x16x32_bf16(ahi[mt], bhi, acc[mt][nt], 0, 0, 0);
        acc[mt][nt] = __builtin_amdgcn_mfma_f32_16x16x32_bf16(ahi[mt], blo, acc[mt][nt], 0, 0, 0);
        acc[mt][nt] = __builtin_amdgcn_mfma_f32_16x16x32_bf16(alo[mt], bhi, acc[mt][nt], 0, 0, 0);
      }
    }
  }

  // ================= epilogue: mask + softmax + confidence =================
  // C/D layout (m89-verified): col = ln15, row = quad*4 + reg (+ mt*16).
  const float NEGINF = -__builtin_inff();

  float rm[4][4];
#pragma unroll
  for (int mt = 0; mt < 4; ++mt)
#pragma unroll
    for (int rg = 0; rg < 4; ++rg) rm[mt][rg] = NEGINF;

#pragma unroll
  for (int nt = 0; nt < 8; ++nt) {
    int col = wn0 + nt * 16 + ln15;
    float kv = Kp[(size_t)col * ND];        // keys[batch][col][0]
    bool msk = (kv == 0.0f);
#pragma unroll
    for (int mt = 0; mt < 4; ++mt)
#pragma unroll
      for (int rg = 0; rg < 4; ++rg) {
        float v = msk ? NEGINF : acc[mt][nt][rg];
        acc[mt][nt][rg] = v;
        rm[mt][rg] = fmaxf(rm[mt][rg], v);
      }
  }
  // reduce max across the 16 lanes sharing a row-set
#pragma unroll
  for (int mt = 0; mt < 4; ++mt)
#pragma unroll
    for (int rg = 0; rg < 4; ++rg) {
      float v = rm[mt][rg];
#pragma unroll
      for (int d = 1; d < 16; d <<= 1) v = fmaxf(v, __shfl_xor(v, d, 64));
      rm[mt][rg] = v;
    }
  if (ln15 == 0) {
#pragma unroll
    for (int mt = 0; mt < 4; ++mt)
#pragma unroll
      for (int rg = 0; rg < 4; ++rg)
        sRedA[w][mt * 16 + quad * 4 + rg] = rm[mt][rg];
  }
  __syncthreads();

  float gmax[4][4], gsum[4][4];
#pragma unroll
  for (int mt = 0; mt < 4; ++mt)
#pragma unroll
    for (int rg = 0; rg < 4; ++rg) {
      int row = mt * 16 + quad * 4 + rg;
      gmax[mt][rg] = fmaxf(fmaxf(sRedA[0][row], sRedA[1][row]),
                           fmaxf(sRedA[2][row], sRedA[3][row]));
      gsum[mt][rg] = 0.f;
    }

#pragma unroll
  for (int nt = 0; nt < 8; ++nt)
#pragma unroll
    for (int mt = 0; mt < 4; ++mt)
#pragma unroll
      for (int rg = 0; rg < 4; ++rg) {
        float e = __expf(acc[mt][nt][rg] - gmax[mt][rg]);
        acc[mt][nt][rg] = e;
        gsum[mt][rg] += e;
      }
#pragma unroll
  for (int mt = 0; mt < 4; ++mt)
#pragma unroll
    for (int rg = 0; rg < 4; ++rg) {
      float v = gsum[mt][rg];
#pragma unroll
      for (int d = 1; d < 16; d <<= 1) v += __shfl_xor(v, d, 64);
      gsum[mt][rg] = v;
    }
  if (ln15 == 0) {
#pragma unroll
    for (int mt = 0; mt < 4; ++mt)
#pragma unroll
      for (int rg = 0; rg < 4; ++rg)
        sRedB[w][mt * 16 + quad * 4 + rg] = gsum[mt][rg];
  }
  __syncthreads();
#pragma unroll
  for (int mt = 0; mt < 4; ++mt)
#pragma unroll
    for (int rg = 0; rg < 4; ++rg) {
      int row = mt * 16 + quad * 4 + rg;
      gsum[mt][rg] = sRedB[0][row] + sRedB[1][row] + sRedB[2][row] + sRedB[3][row];
    }

  // attn output
  float* outBase = attn + ((size_t)batch * NQ + q0) * NK;
#pragma unroll
  for (int mt = 0; mt < 4; ++mt)
#pragma unroll
    for (int rg = 0; rg < 4; ++rg) {
      int row = mt * 16 + quad * 4 + rg;
      float inv = 1.0f / gsum[mt][rg];
#pragma unroll
      for (int nt = 0; nt < 8; ++nt) {
        int col = wn0 + nt * 16 + ln15;
        outBase[(size_t)row * NK + col] = acc[mt][nt][rg] * inv;
      }
    }

  // confidence = sigmoid((logsumexp + bias) * temperature), wave 0 writes
  if (w == 0 && ln15 == 0) {
    float tv = Tp[0], bv = Bp[0];
#pragma unroll
    for (int mt = 0; mt < 4; ++mt)
#pragma unroll
      for (int rg = 0; rg < 4; ++rg) {
        int row = mt * 16 + quad * 4 + rg;
        float lse = gmax[mt][rg] + __logf(gsum[mt][rg]);
        float t = (lse + bv) * tv;
        conf[(size_t)batch * NQ + q0 + row] = 1.0f / (1.0f + __expf(-t));
      }
  }
}

extern "C" void kernel_launch(void* const* d_in, const int* in_sizes, int n_in,
                              void* d_out, int out_size, void* d_ws, size_t ws_size,
                              hipStream_t stream) {
  const float* q = (const float*)d_in[0];
  const float* k = (const float*)d_in[1];
  const float* temp = (const float*)d_in[2];
  const float* bias = (const float*)d_in[3];
  float* attn = (float*)d_out;
  float* conf = attn + (size_t)NB * NQ * NK;

  dim3 grid(NB * (NQ / BM));  // 256 blocks
  dim3 block(256);
  hipLaunchKernelGGL(attn_fused, grid, block, 0, stream, q, k, temp, bias, attn, conf);
}

// Round 2
// 226.893 us; speedup vs baseline: 1.0579x; 1.0579x over previous
//
#include <hip/hip_runtime.h>
#include <math.h>
#include <stdint.h>

// ContentAttention fused, round 2.
// Kernel 1 (convert_k): K fp32 -> bf16 hi/lo tiles in ws, pre-swizzled into the
//   exact LDS image the main kernel DMAs in via global_load_lds. Also emits
//   mask[b][k] = K[b][k][0] compactly. Removes the 8x-redundant per-block
//   conversion VALU that dominated R1 (VALUBusy 30% at 1 wave/SIMD).
// Kernel 2 (attn_fused_v2): BM=32 -> grid 512 = 2 blocks/CU (R1 had 1 block/CU,
//   occupancy 10.9%, zero latency hiding). B staging is pure DMA.
// Fallback to the R1 kernel if ws_size is too small.

#define NB 32
#define NQ 512
#define NK 512
#define ND 1024
#define BK 32
#define NT (ND / BK)            // 32 k-tiles
#define BM1 64                  // fallback (R1) rows/block
#define BM2 32                  // v2 rows/block
#define TILE_BYTES 65536        // per (batch,kt): 32KB hi + 32KB lo
#define WS_TILES ((size_t)NB * NT * TILE_BYTES)        // 64 MiB
#define WS_TOTAL (WS_TILES + (size_t)NB * NK * 4)      // + mask 64 KiB

typedef __attribute__((ext_vector_type(8))) short short8;
typedef __attribute__((ext_vector_type(4))) float f32x4;

// Split fp32 x into bf16 hi (RN, as high-bits float) and fp32 residual lo.
__device__ __forceinline__ void bf_split(float x, unsigned& hbits, float& lo) {
  unsigned u = __float_as_uint(x);
  unsigned r = u + 0x7fffu + ((u >> 16) & 1u);
  hbits = r & 0xffff0000u;
  lo = x - __uint_as_float(hbits);
}
__device__ __forceinline__ unsigned pack_rn(float x0, float x1) {
  unsigned u0 = __float_as_uint(x0), u1 = __float_as_uint(x1);
  unsigned r0 = u0 + 0x7fffu + ((u0 >> 16) & 1u);
  unsigned r1 = u1 + 0x7fffu + ((u1 >> 16) & 1u);
  return (r0 >> 16) | (r1 & 0xffff0000u);
}

// Rotated LDS image: 32 bf16 (64 B) per row; 16B chunk slot rotated by row>>1
// so 16-lane frag reads spread 2-way over all bank groups (2-way free, m136).
__device__ __forceinline__ int lds_off_write(int r, int c4) {
  int slot = ((c4 >> 1) + (r >> 1)) & 3;
  return r * 32 + slot * 8 + (c4 & 1) * 4;   // ushort units
}
__device__ __forceinline__ int lds_off_read(int r, int quad) {
  int slot = (quad + (r >> 1)) & 3;
  return r * 32 + slot * 8;                  // ushort units (16B frag)
}

// Async global->LDS 16B copy. LDS dest is wave-uniform base + lane*16 (m104);
// we always compute lds as base + lane*16-contiguous, matching ws layout.
__device__ __forceinline__ void gl2lds16(const void* g, void* l) {
  __builtin_amdgcn_global_load_lds(
      (const __attribute__((address_space(1))) unsigned int*)g,
      (__attribute__((address_space(3))) unsigned int*)l, 16, 0, 0);
}

// ---------------------------------------------------------------------------
// Kernel 1: K fp32 -> ws (rotated hi/lo bf16 tiles) + mask floats
// ---------------------------------------------------------------------------
__global__ __launch_bounds__(256)
void convert_k(const float* __restrict__ Kg, unsigned char* __restrict__ ws) {
  const int bx = blockIdx.x;          // 0..1023
  const int batch = bx >> 5, kt = bx & 31;
  const float* src = Kg + (size_t)batch * NK * ND + kt * BK;
  unsigned short* hiB = (unsigned short*)(ws + (size_t)bx * TILE_BYTES);
  unsigned short* loB = hiB + 32768 / 2;
  float* maskB = (float*)(ws + WS_TILES) + batch * NK;

#pragma unroll
  for (int i = 0; i < 16; ++i) {
    int idx = threadIdx.x + 256 * i;
    int r = idx >> 3, c4 = idx & 7;
    float4 v = *(const float4*)(src + (size_t)r * ND + c4 * 4);
    unsigned h0, h1, h2, h3;
    float l0, l1, l2, l3;
    bf_split(v.x, h0, l0); bf_split(v.y, h1, l1);
    bf_split(v.z, h2, l2); bf_split(v.w, h3, l3);
    int off = lds_off_write(r, c4);
    *(uint2*)(&hiB[off]) = make_uint2((h0 >> 16) | h1, (h2 >> 16) | h3);
    *(uint2*)(&loB[off]) = make_uint2(pack_rn(l0, l1), pack_rn(l2, l3));
    if (kt == 0 && c4 == 0) maskB[r] = v.x;   // K[b][r][0] for the key mask
  }
}

// ---------------------------------------------------------------------------
// Kernel 2: fused QK^T (bf16 hi/lo 3-product MFMA) + masked softmax + conf
// ---------------------------------------------------------------------------
__global__ __launch_bounds__(256, 2)
void attn_fused_v2(const float* __restrict__ Qg,
                   const unsigned char* __restrict__ ws,
                   const float* __restrict__ Tp, const float* __restrict__ Bp,
                   float* __restrict__ attn, float* __restrict__ conf) {
  __shared__ __align__(16) unsigned short sBhi[NK * BK];   // 32 KB
  __shared__ __align__(16) unsigned short sBlo[NK * BK];   // 32 KB
  __shared__ __align__(16) unsigned short sAhi[BM2 * BK];  // 2 KB
  __shared__ __align__(16) unsigned short sAlo[BM2 * BK];  // 2 KB
  __shared__ float sRedA[4][BM2];
  __shared__ float sRedB[4][BM2];

  const int tid = threadIdx.x;
  const int g = blockIdx.x;                       // 0..511
  // XCD swizzle: all 16 q-tile blocks of a batch land on one XCD (g%8 rr).
  const int batch = (g & 7) | (((g >> 3) & 3) << 3);
  const int q0 = (g >> 5) * BM2;                  // 16 q-tiles
  const int ln = tid & 63, w = tid >> 6;
  const int ln15 = ln & 15, quad = ln >> 4;
  const int wn0 = w * 128;

  const float* Qp = Qg + ((size_t)batch * NQ + q0) * ND;
  const unsigned char* wsB = ws + (size_t)batch * NT * TILE_BYTES;
  const float* maskB = (const float*)(ws + WS_TILES) + batch * NK;

  f32x4 acc[2][8];
#pragma unroll
  for (int mt = 0; mt < 2; ++mt)
#pragma unroll
    for (int nt = 0; nt < 8; ++nt) acc[mt][nt] = (f32x4){0.f, 0.f, 0.f, 0.f};

  // A prefetch tile 0 (1 float4/thread covers the 32x32 fp32 A tile)
  const int ar = tid >> 3, ac4 = tid & 7;
  float4 pa = *(const float4*)(Qp + (size_t)ar * ND + ac4 * 4);

  for (int kt = 0; kt < NT; ++kt) {
    if (kt) __syncthreads();   // prev tile's frag reads done before overwrite

    // ---- B staging: pure DMA from pre-converted ws (no VALU) ----
    const unsigned char* tb = wsB + (size_t)kt * TILE_BYTES;
#pragma unroll
    for (int c = 0; c < 8; ++c) {
      int byte = (((c * 4 + w) * 64) + ln) * 16;  // wave-contiguous chunks
      gl2lds16(tb + byte, ((unsigned char*)sBhi) + byte);
      gl2lds16(tb + 32768 + byte, ((unsigned char*)sBlo) + byte);
    }
    // ---- A staging: convert prefetched fp32 ----
    {
      unsigned h0, h1, h2, h3;
      float l0, l1, l2, l3;
      bf_split(pa.x, h0, l0); bf_split(pa.y, h1, l1);
      bf_split(pa.z, h2, l2); bf_split(pa.w, h3, l3);
      int off = lds_off_write(ar, ac4);
      *(uint2*)(&sAhi[off]) = make_uint2((h0 >> 16) | h1, (h2 >> 16) | h3);
      *(uint2*)(&sAlo[off]) = make_uint2(pack_rn(l0, l1), pack_rn(l2, l3));
    }
    __syncthreads();           // drains DMA (vmcnt) + A writes

    if (kt + 1 < NT)           // next A tile; hides under frag reads + MFMA
      pa = *(const float4*)(Qp + (kt + 1) * BK + (size_t)ar * ND + ac4 * 4);

    // ---- fragments + MFMA (3-product hi/lo) ----
    short8 ahi[2], alo[2];
#pragma unroll
    for (int mt = 0; mt < 2; ++mt) {
      int off = lds_off_read(mt * 16 + ln15, quad);
      ahi[mt] = *(const short8*)(&sAhi[off]);
      alo[mt] = *(const short8*)(&sAlo[off]);
    }
#pragma unroll
    for (int nt = 0; nt < 8; ++nt) {
      int off = lds_off_read(wn0 + nt * 16 + ln15, quad);
      short8 bhi = *(const short8*)(&sBhi[off]);
      short8 blo = *(const short8*)(&sBlo[off]);
#pragma unroll
      for (int mt = 0; mt < 2; ++mt) {
        acc[mt][nt] = __builtin_amdgcn_mfma_f32_16x16x32_bf16(ahi[mt], bhi, acc[mt][nt], 0, 0, 0);
        acc[mt][nt] = __builtin_amdgcn_mfma_f32_16x16x32_bf16(ahi[mt], blo, acc[mt][nt], 0, 0, 0);
        acc[mt][nt] = __builtin_amdgcn_mfma_f32_16x16x32_bf16(alo[mt], bhi, acc[mt][nt], 0, 0, 0);
      }
    }
  }

  // ============== epilogue: mask + softmax + confidence ==============
  const float NEGINF = -__builtin_inff();
  float rm[2][4];
#pragma unroll
  for (int mt = 0; mt < 2; ++mt)
#pragma unroll
    for (int rg = 0; rg < 4; ++rg) rm[mt][rg] = NEGINF;

#pragma unroll
  for (int nt = 0; nt < 8; ++nt) {
    int col = wn0 + nt * 16 + ln15;
    bool msk = (maskB[col] == 0.0f);
#pragma unroll
    for (int mt = 0; mt < 2; ++mt)
#pragma unroll
      for (int rg = 0; rg < 4; ++rg) {
        float v = msk ? NEGINF : acc[mt][nt][rg];
        acc[mt][nt][rg] = v;
        rm[mt][rg] = fmaxf(rm[mt][rg], v);
      }
  }
#pragma unroll
  for (int mt = 0; mt < 2; ++mt)
#pragma unroll
    for (int rg = 0; rg < 4; ++rg) {
      float v = rm[mt][rg];
#pragma unroll
      for (int d = 1; d < 16; d <<= 1) v = fmaxf(v, __shfl_xor(v, d, 64));
      rm[mt][rg] = v;
    }
  if (ln15 == 0) {
#pragma unroll
    for (int mt = 0; mt < 2; ++mt)
#pragma unroll
      for (int rg = 0; rg < 4; ++rg)
        sRedA[w][mt * 16 + quad * 4 + rg] = rm[mt][rg];
  }
  __syncthreads();

  float gmax[2][4], gsum[2][4];
#pragma unroll
  for (int mt = 0; mt < 2; ++mt)
#pragma unroll
    for (int rg = 0; rg < 4; ++rg) {
      int row = mt * 16 + quad * 4 + rg;
      gmax[mt][rg] = fmaxf(fmaxf(sRedA[0][row], sRedA[1][row]),
                           fmaxf(sRedA[2][row], sRedA[3][row]));
      gsum[mt][rg] = 0.f;
    }

#pragma unroll
  for (int nt = 0; nt < 8; ++nt)
#pragma unroll
    for (int mt = 0; mt < 2; ++mt)
#pragma unroll
      for (int rg = 0; rg < 4; ++rg) {
        float e = __expf(acc[mt][nt][rg] - gmax[mt][rg]);
        acc[mt][nt][rg] = e;
        gsum[mt][rg] += e;
      }
#pragma unroll
  for (int mt = 0; mt < 2; ++mt)
#pragma unroll
    for (int rg = 0; rg < 4; ++rg) {
      float v = gsum[mt][rg];
#pragma unroll
      for (int d = 1; d < 16; d <<= 1) v += __shfl_xor(v, d, 64);
      gsum[mt][rg] = v;
    }
  if (ln15 == 0) {
#pragma unroll
    for (int mt = 0; mt < 2; ++mt)
#pragma unroll
      for (int rg = 0; rg < 4; ++rg)
        sRedB[w][mt * 16 + quad * 4 + rg] = gsum[mt][rg];
  }
  __syncthreads();
#pragma unroll
  for (int mt = 0; mt < 2; ++mt)
#pragma unroll
    for (int rg = 0; rg < 4; ++rg) {
      int row = mt * 16 + quad * 4 + rg;
      gsum[mt][rg] = sRedB[0][row] + sRedB[1][row] + sRedB[2][row] + sRedB[3][row];
    }

  float* outBase = attn + ((size_t)batch * NQ + q0) * NK;
#pragma unroll
  for (int mt = 0; mt < 2; ++mt)
#pragma unroll
    for (int rg = 0; rg < 4; ++rg) {
      int row = mt * 16 + quad * 4 + rg;
      float inv = 1.0f / gsum[mt][rg];
#pragma unroll
      for (int nt = 0; nt < 8; ++nt)
        outBase[(size_t)row * NK + wn0 + nt * 16 + ln15] = acc[mt][nt][rg] * inv;
    }

  if (w == 0 && ln15 == 0) {
    float tv = Tp[0], bv = Bp[0];
#pragma unroll
    for (int mt = 0; mt < 2; ++mt)
#pragma unroll
      for (int rg = 0; rg < 4; ++rg) {
        int row = mt * 16 + quad * 4 + rg;
        float lse = gmax[mt][rg] + __logf(gsum[mt][rg]);
        float t = (lse + bv) * tv;
        conf[(size_t)batch * NQ + q0 + row] = 1.0f / (1.0f + __expf(-t));
      }
  }
}

// ---------------------------------------------------------------------------
// Fallback: R1 single-kernel path (used only if ws_size < WS_TOTAL)
// ---------------------------------------------------------------------------
__global__ __launch_bounds__(256, 1)
void attn_fused_v1(const float* __restrict__ Qg, const float* __restrict__ Kg,
                   const float* __restrict__ Tp, const float* __restrict__ Bp,
                   float* __restrict__ attn, float* __restrict__ conf) {
  __shared__ __align__(16) unsigned short sAhi[BM1 * BK];
  __shared__ __align__(16) unsigned short sAlo[BM1 * BK];
  __shared__ __align__(16) unsigned short sBhi[NK * BK];
  __shared__ __align__(16) unsigned short sBlo[NK * BK];
  __shared__ float sRedA[4][BM1];
  __shared__ float sRedB[4][BM1];

  const int tid = threadIdx.x;
  const int g = blockIdx.x;
  const int batch = (g & 7) | (((g >> 3) & 3) << 3);
  const int q0 = (g >> 5) * BM1;
  const int ln = tid & 63, w = tid >> 6;
  const int ln15 = ln & 15, quad = ln >> 4;
  const int wn0 = w * 128;

  const float* Qp = Qg + ((size_t)batch * NQ + q0) * ND;
  const float* Kp = Kg + (size_t)batch * NK * ND;

  f32x4 acc[4][8];
#pragma unroll
  for (int mt = 0; mt < 4; ++mt)
#pragma unroll
    for (int nt = 0; nt < 8; ++nt) acc[mt][nt] = (f32x4){0.f, 0.f, 0.f, 0.f};

  float4 pb[16], pa[2];
#pragma unroll
  for (int i = 0; i < 16; ++i) {
    int idx = tid + 256 * i, r = idx >> 3, c4 = idx & 7;
    pb[i] = *(const float4*)(Kp + (size_t)r * ND + c4 * 4);
  }
#pragma unroll
  for (int i = 0; i < 2; ++i) {
    int idx = tid + 256 * i, r = idx >> 3, c4 = idx & 7;
    pa[i] = *(const float4*)(Qp + (size_t)r * ND + c4 * 4);
  }

  for (int kt = 0; kt < NT; ++kt) {
    if (kt) __syncthreads();
#pragma unroll
    for (int i = 0; i < 2; ++i) {
      int idx = tid + 256 * i, r = idx >> 3, c4 = idx & 7;
      int off = lds_off_write(r, c4);
      unsigned h0, h1, h2, h3; float l0, l1, l2, l3;
      bf_split(pa[i].x, h0, l0); bf_split(pa[i].y, h1, l1);
      bf_split(pa[i].z, h2, l2); bf_split(pa[i].w, h3, l3);
      *(uint2*)(&sAhi[off]) = make_uint2((h0 >> 16) | h1, (h2 >> 16) | h3);
      *(uint2*)(&sAlo[off]) = make_uint2(pack_rn(l0, l1), pack_rn(l2, l3));
    }
#pragma unroll
    for (int i = 0; i < 16; ++i) {
      int idx = tid + 256 * i, r = idx >> 3, c4 = idx & 7;
      int off = lds_off_write(r, c4);
      unsigned h0, h1, h2, h3; float l0, l1, l2, l3;
      bf_split(pb[i].x, h0, l0); bf_split(pb[i].y, h1, l1);
      bf_split(pb[i].z, h2, l2); bf_split(pb[i].w, h3, l3);
      *(uint2*)(&sBhi[off]) = make_uint2((h0 >> 16) | h1, (h2 >> 16) | h3);
      *(uint2*)(&sBlo[off]) = make_uint2(pack_rn(l0, l1), pack_rn(l2, l3));
    }
    __syncthreads();

    if (kt < NT - 1) {
      const float* Kq = Kp + (kt + 1) * BK;
      const float* Qq = Qp + (kt + 1) * BK;
#pragma unroll
      for (int i = 0; i < 16; ++i) {
        int idx = tid + 256 * i, r = idx >> 3, c4 = idx & 7;
        pb[i] = *(const float4*)(Kq + (size_t)r * ND + c4 * 4);
      }
#pragma unroll
      for (int i = 0; i < 2; ++i) {
        int idx = tid + 256 * i, r = idx >> 3, c4 = idx & 7;
        pa[i] = *(const float4*)(Qq + (size_t)r * ND + c4 * 4);
      }
    }

    short8 ahi[4], alo[4];
#pragma unroll
    for (int mt = 0; mt < 4; ++mt) {
      int off = lds_off_read(mt * 16 + ln15, quad);
      ahi[mt] = *(const short8*)(&sAhi[off]);
      alo[mt] = *(const short8*)(&sAlo[off]);
    }
#pragma unroll
    for (int nt = 0; nt < 8; ++nt) {
      int off = lds_off_read(wn0 + nt * 16 + ln15, quad);
      short8 bhi = *(const short8*)(&sBhi[off]);
      short8 blo = *(const short8*)(&sBlo[off]);
#pragma unroll
      for (int mt = 0; mt < 4; ++mt) {
        acc[mt][nt] = __builtin_amdgcn_mfma_f32_16x16x32_bf16(ahi[mt], bhi, acc[mt][nt], 0, 0, 0);
        acc[mt][nt] = __builtin_amdgcn_mfma_f32_16x16x32_bf16(ahi[mt], blo, acc[mt][nt], 0, 0, 0);
        acc[mt][nt] = __builtin_amdgcn_mfma_f32_16x16x32_bf16(alo[mt], bhi, acc[mt][nt], 0, 0, 0);
      }
    }
  }

  const float NEGINF = -__builtin_inff();
  float rm[4][4];
#pragma unroll
  for (int mt = 0; mt < 4; ++mt)
#pragma unroll
    for (int rg = 0; rg < 4; ++rg) rm[mt][rg] = NEGINF;
#pragma unroll
  for (int nt = 0; nt < 8; ++nt) {
    int col = wn0 + nt * 16 + ln15;
    bool msk = (Kp[(size_t)col * ND] == 0.0f);
#pragma unroll
    for (int mt = 0; mt < 4; ++mt)
#pragma unroll
      for (int rg = 0; rg < 4; ++rg) {
        float v = msk ? NEGINF : acc[mt][nt][rg];
        acc[mt][nt][rg] = v;
        rm[mt][rg] = fmaxf(rm[mt][rg], v);
      }
  }
#pragma unroll
  for (int mt = 0; mt < 4; ++mt)
#pragma unroll
    for (int rg = 0; rg < 4; ++rg) {
      float v = rm[mt][rg];
#pragma unroll
      for (int d = 1; d < 16; d <<= 1) v = fmaxf(v, __shfl_xor(v, d, 64));
      rm[mt][rg] = v;
    }
  if (ln15 == 0)
#pragma unroll
    for (int mt = 0; mt < 4; ++mt)
#pragma unroll
      for (int rg = 0; rg < 4; ++rg)
        sRedA[w][mt * 16 + quad * 4 + rg] = rm[mt][rg];
  __syncthreads();

  float gmax[4][4], gsum[4][4];
#pragma unroll
  for (int mt = 0; mt < 4; ++mt)
#pragma unroll
    for (int rg = 0; rg < 4; ++rg) {
      int row = mt * 16 + quad * 4 + rg;
      gmax[mt][rg] = fmaxf(fmaxf(sRedA[0][row], sRedA[1][row]),
                           fmaxf(sRedA[2][row], sRedA[3][row]));
      gsum[mt][rg] = 0.f;
    }
#pragma unroll
  for (int nt = 0; nt < 8; ++nt)
#pragma unroll
    for (int mt = 0; mt < 4; ++mt)
#pragma unroll
      for (int rg = 0; rg < 4; ++rg) {
        float e = __expf(acc[mt][nt][rg] - gmax[mt][rg]);
        acc[mt][nt][rg] = e;
        gsum[mt][rg] += e;
      }
#pragma unroll
  for (int mt = 0; mt < 4; ++mt)
#pragma unroll
    for (int rg = 0; rg < 4; ++rg) {
      float v = gsum[mt][rg];
#pragma unroll
      for (int d = 1; d < 16; d <<= 1) v += __shfl_xor(v, d, 64);
      gsum[mt][rg] = v;
    }
  if (ln15 == 0)
#pragma unroll
    for (int mt = 0; mt < 4; ++mt)
#pragma unroll
      for (int rg = 0; rg < 4; ++rg)
        sRedB[w][mt * 16 + quad * 4 + rg] = gsum[mt][rg];
  __syncthreads();
#pragma unroll
  for (int mt = 0; mt < 4; ++mt)
#pragma unroll
    for (int rg = 0; rg < 4; ++rg) {
      int row = mt * 16 + quad * 4 + rg;
      gsum[mt][rg] = sRedB[0][row] + sRedB[1][row] + sRedB[2][row] + sRedB[3][row];
    }

  float* outBase = attn + ((size_t)batch * NQ + q0) * NK;
#pragma unroll
  for (int mt = 0; mt < 4; ++mt)
#pragma unroll
    for (int rg = 0; rg < 4; ++rg) {
      int row = mt * 16 + quad * 4 + rg;
      float inv = 1.0f / gsum[mt][rg];
#pragma unroll
      for (int nt = 0; nt < 8; ++nt)
        outBase[(size_t)row * NK + wn0 + nt * 16 + ln15] = acc[mt][nt][rg] * inv;
    }
  if (w == 0 && ln15 == 0) {
    float tv = Tp[0], bv = Bp[0];
#pragma unroll
    for (int mt = 0; mt < 4; ++mt)
#pragma unroll
      for (int rg = 0; rg < 4; ++rg) {
        int row = mt * 16 + quad * 4 + rg;
        float lse = gmax[mt][rg] + __logf(gsum[mt][rg]);
        float t = (lse + bv) * tv;
        conf[(size_t)batch * NQ + q0 + row] = 1.0f / (1.0f + __expf(-t));
      }
  }
}

extern "C" void kernel_launch(void* const* d_in, const int* in_sizes, int n_in,
                              void* d_out, int out_size, void* d_ws, size_t ws_size,
                              hipStream_t stream) {
  const float* q = (const float*)d_in[0];
  const float* k = (const float*)d_in[1];
  const float* temp = (const float*)d_in[2];
  const float* bias = (const float*)d_in[3];
  float* attn = (float*)d_out;
  float* conf = attn + (size_t)NB * NQ * NK;

  if (ws_size >= WS_TOTAL) {
    hipLaunchKernelGGL(convert_k, dim3(NB * NT), dim3(256), 0, stream,
                       k, (unsigned char*)d_ws);
    hipLaunchKernelGGL(attn_fused_v2, dim3(NB * (NQ / BM2)), dim3(256), 0, stream,
                       q, (const unsigned char*)d_ws, temp, bias, attn, conf);
  } else {
    hipLaunchKernelGGL(attn_fused_v1, dim3(NB * (NQ / BM1)), dim3(256), 0, stream,
                       q, k, temp, bias, attn, conf);
  }
}

// Round 3
// 219.605 us; speedup vs baseline: 1.0930x; 1.0332x over previous
//
#include <hip/hip_runtime.h>
#include <math.h>
#include <stdint.h>

// ContentAttention fused, round 3.
// convert_k: unchanged from R2 (K fp32 -> pre-swizzled bf16 hi/lo tiles in ws).
// attn_fused_v3: BM=64 (halves ws re-stream to 512 MB), 1024-thread blocks
//   (16 waves/CU), double-buffered LDS (148 KB, 1 block/CU) with ONE barrier
//   per k-tile: DMA for tile t+1 is issued right after the barrier and drained
//   only at the NEXT barrier, a full compute phase later. This removes the
//   R2 issue->barrier->drain serialization (97 us at MfmaUtil 20%, busy-pipe
//   sum ~50 us => latency-bound).
// Fallback v1 kept for ws_size < WS_TOTAL.

#define NB 32
#define NQ 512
#define NK 512
#define ND 1024
#define BK 32
#define NT (ND / BK)            // 32 k-tiles
#define BM1 64                  // fallback (R1) rows/block
#define BM3 64                  // v3 rows/block
#define TILE_BYTES 65536        // per (batch,kt): 32KB hi + 32KB lo
#define WS_TILES ((size_t)NB * NT * TILE_BYTES)        // 64 MiB
#define WS_TOTAL (WS_TILES + (size_t)NB * NK * 4)      // + mask 64 KiB

typedef __attribute__((ext_vector_type(8))) short short8;
typedef __attribute__((ext_vector_type(4))) float f32x4;

__device__ __forceinline__ void bf_split(float x, unsigned& hbits, float& lo) {
  unsigned u = __float_as_uint(x);
  unsigned r = u + 0x7fffu + ((u >> 16) & 1u);
  hbits = r & 0xffff0000u;
  lo = x - __uint_as_float(hbits);
}
__device__ __forceinline__ unsigned pack_rn(float x0, float x1) {
  unsigned u0 = __float_as_uint(x0), u1 = __float_as_uint(x1);
  unsigned r0 = u0 + 0x7fffu + ((u0 >> 16) & 1u);
  unsigned r1 = u1 + 0x7fffu + ((u1 >> 16) & 1u);
  return (r0 >> 16) | (r1 & 0xffff0000u);
}

// Rotated LDS image: 64B rows, 16B chunk slot rotated by row>>1 (2-way on all
// bank groups for both frag reads and staging writes; 2-way is free, m136).
__device__ __forceinline__ int lds_off_write(int r, int c4) {
  int slot = ((c4 >> 1) + (r >> 1)) & 3;
  return r * 32 + slot * 8 + (c4 & 1) * 4;   // ushort units
}
__device__ __forceinline__ int lds_off_read(int r, int quad) {
  int slot = (quad + (r >> 1)) & 3;
  return r * 32 + slot * 8;                  // ushort units (16B frag)
}

__device__ __forceinline__ void gl2lds16(const void* g, void* l) {
  __builtin_amdgcn_global_load_lds(
      (const __attribute__((address_space(1))) unsigned int*)g,
      (__attribute__((address_space(3))) unsigned int*)l, 16, 0, 0);
}

// ---------------------------------------------------------------------------
// Kernel 1: K fp32 -> ws (rotated hi/lo bf16 tiles) + mask floats (unchanged)
// ---------------------------------------------------------------------------
__global__ __launch_bounds__(256)
void convert_k(const float* __restrict__ Kg, unsigned char* __restrict__ ws) {
  const int bx = blockIdx.x;          // 0..1023
  const int batch = bx >> 5, kt = bx & 31;
  const float* src = Kg + (size_t)batch * NK * ND + kt * BK;
  unsigned short* hiB = (unsigned short*)(ws + (size_t)bx * TILE_BYTES);
  unsigned short* loB = hiB + 32768 / 2;
  float* maskB = (float*)(ws + WS_TILES) + batch * NK;

#pragma unroll
  for (int i = 0; i < 16; ++i) {
    int idx = threadIdx.x + 256 * i;
    int r = idx >> 3, c4 = idx & 7;
    float4 v = *(const float4*)(src + (size_t)r * ND + c4 * 4);
    unsigned h0, h1, h2, h3;
    float l0, l1, l2, l3;
    bf_split(v.x, h0, l0); bf_split(v.y, h1, l1);
    bf_split(v.z, h2, l2); bf_split(v.w, h3, l3);
    int off = lds_off_write(r, c4);
    *(uint2*)(&hiB[off]) = make_uint2((h0 >> 16) | h1, (h2 >> 16) | h3);
    *(uint2*)(&loB[off]) = make_uint2(pack_rn(l0, l1), pack_rn(l2, l3));
    if (kt == 0 && c4 == 0) maskB[r] = v.x;
  }
}

// ---------------------------------------------------------------------------
// v3 staging helpers
// ---------------------------------------------------------------------------
__device__ __forceinline__ void stage_a(unsigned short* hiA, unsigned short* loA,
                                        int ar, int ac4, float4 v) {
  unsigned h0, h1, h2, h3;
  float l0, l1, l2, l3;
  bf_split(v.x, h0, l0); bf_split(v.y, h1, l1);
  bf_split(v.z, h2, l2); bf_split(v.w, h3, l3);
  int off = lds_off_write(ar, ac4);
  *(uint2*)(&hiA[off]) = make_uint2((h0 >> 16) | h1, (h2 >> 16) | h3);
  *(uint2*)(&loA[off]) = make_uint2(pack_rn(l0, l1), pack_rn(l2, l3));
}

// Each wave DMAs 4 KB: chunks w and w+16 of both hi (32 KB) and lo (32 KB).
__device__ __forceinline__ void stage_b(const unsigned char* tb,
                                        unsigned short* hiB, unsigned short* loB,
                                        int w, int ln) {
  int b0 = (w * 64 + ln) * 16;
  int b1 = ((16 + w) * 64 + ln) * 16;
  gl2lds16(tb + b0, ((unsigned char*)hiB) + b0);
  gl2lds16(tb + b1, ((unsigned char*)hiB) + b1);
  gl2lds16(tb + 32768 + b0, ((unsigned char*)loB) + b0);
  gl2lds16(tb + 32768 + b1, ((unsigned char*)loB) + b1);
}

// ---------------------------------------------------------------------------
// Kernel 2 (v3): BM=64, 16 waves, dbuf LDS, one barrier per k-tile
// ---------------------------------------------------------------------------
__global__ __launch_bounds__(1024, 4)
void attn_fused_v3(const float* __restrict__ Qg,
                   const unsigned char* __restrict__ ws,
                   const float* __restrict__ Tp, const float* __restrict__ Bp,
                   float* __restrict__ attn, float* __restrict__ conf) {
  __shared__ __align__(16) unsigned short sBhi[2][NK * BK];   // 2 x 32 KB
  __shared__ __align__(16) unsigned short sBlo[2][NK * BK];   // 2 x 32 KB
  __shared__ __align__(16) unsigned short sAhi[2][BM3 * BK];  // 2 x 4 KB
  __shared__ __align__(16) unsigned short sAlo[2][BM3 * BK];  // 2 x 4 KB
  __shared__ float sRedA[8][BM3];                              // 2 KB
  __shared__ float sRedB[8][BM3];                              // 2 KB

  const int tid = threadIdx.x;
  const int g = blockIdx.x;                       // 0..255
  const int batch = (g & 7) | (((g >> 3) & 3) << 3);   // co-XCD per batch
  const int q0 = (g >> 5) * BM3;                  // 8 q-chunks of 64
  const int ln = tid & 63, w = tid >> 6;          // w: 0..15
  const int ln15 = ln & 15, quad = ln >> 4;
  const int wc = w & 7, wr = w >> 3;              // 8 col-groups x 2 row-groups
  const int row0 = wr * 32, col0 = wc * 64;

  const float* Qp = Qg + ((size_t)batch * NQ + q0) * ND;
  const unsigned char* wsB = ws + (size_t)batch * NT * TILE_BYTES;
  const float* maskB = (const float*)(ws + WS_TILES) + batch * NK;

  f32x4 acc[2][4];
#pragma unroll
  for (int mt = 0; mt < 2; ++mt)
#pragma unroll
    for (int nt = 0; nt < 4; ++nt) acc[mt][nt] = (f32x4){0.f, 0.f, 0.f, 0.f};

  // A staging owned by waves 0..7 (wave-uniform predicate, no divergence).
  const bool aload = (tid < 512);
  const int ar = tid >> 3, ac4 = tid & 7;         // 64 rows x 8 float4

  // ---- prologue: stage tile 0, prefetch A(1) ----
  float4 pa = (float4){0.f, 0.f, 0.f, 0.f};
  if (aload) {
    float4 a0 = *(const float4*)(Qp + (size_t)ar * ND + ac4 * 4);
    stage_a(sAhi[0], sAlo[0], ar, ac4, a0);
    pa = *(const float4*)(Qp + BK + (size_t)ar * ND + ac4 * 4);
  }
  stage_b(wsB, sBhi[0], sBlo[0], w, ln);

  for (int kt = 0; kt < NT; ++kt) {
    const int cur = kt & 1, nxt = cur ^ 1;
    // Drains: (a) DMA for buf[cur] issued one full tile ago, (b) everyone's
    // frag reads of buf[nxt] from tile kt-1 (safe to overwrite).
    __syncthreads();

    if (kt + 1 < NT) {
      stage_b(wsB + (size_t)(kt + 1) * TILE_BYTES, sBhi[nxt], sBlo[nxt], w, ln);
      if (aload) {
        stage_a(sAhi[nxt], sAlo[nxt], ar, ac4, pa);
        if (kt + 2 < NT)
          pa = *(const float4*)(Qp + (kt + 2) * BK + (size_t)ar * ND + ac4 * 4);
      }
    }

    // ---- fragments + MFMA on buf[cur] (hi/lo 3-product) ----
    short8 ahi[2], alo[2];
#pragma unroll
    for (int mt = 0; mt < 2; ++mt) {
      int off = lds_off_read(row0 + mt * 16 + ln15, quad);
      ahi[mt] = *(const short8*)(&sAhi[cur][off]);
      alo[mt] = *(const short8*)(&sAlo[cur][off]);
    }
#pragma unroll
    for (int nt = 0; nt < 4; ++nt) {
      int off = lds_off_read(col0 + nt * 16 + ln15, quad);
      short8 bhi = *(const short8*)(&sBhi[cur][off]);
      short8 blo = *(const short8*)(&sBlo[cur][off]);
#pragma unroll
      for (int mt = 0; mt < 2; ++mt) {
        acc[mt][nt] = __builtin_amdgcn_mfma_f32_16x16x32_bf16(ahi[mt], bhi, acc[mt][nt], 0, 0, 0);
        acc[mt][nt] = __builtin_amdgcn_mfma_f32_16x16x32_bf16(ahi[mt], blo, acc[mt][nt], 0, 0, 0);
        acc[mt][nt] = __builtin_amdgcn_mfma_f32_16x16x32_bf16(alo[mt], bhi, acc[mt][nt], 0, 0, 0);
      }
    }
  }

  // ============== epilogue: mask + softmax + confidence ==============
  const float NEGINF = -__builtin_inff();
  float rm[2][4];
#pragma unroll
  for (int mt = 0; mt < 2; ++mt)
#pragma unroll
    for (int rg = 0; rg < 4; ++rg) rm[mt][rg] = NEGINF;

#pragma unroll
  for (int nt = 0; nt < 4; ++nt) {
    int col = col0 + nt * 16 + ln15;
    bool msk = (maskB[col] == 0.0f);
#pragma unroll
    for (int mt = 0; mt < 2; ++mt)
#pragma unroll
      for (int rg = 0; rg < 4; ++rg) {
        float v = msk ? NEGINF : acc[mt][nt][rg];
        acc[mt][nt][rg] = v;
        rm[mt][rg] = fmaxf(rm[mt][rg], v);
      }
  }
#pragma unroll
  for (int mt = 0; mt < 2; ++mt)
#pragma unroll
    for (int rg = 0; rg < 4; ++rg) {
      float v = rm[mt][rg];
#pragma unroll
      for (int d = 1; d < 16; d <<= 1) v = fmaxf(v, __shfl_xor(v, d, 64));
      rm[mt][rg] = v;
    }
  __syncthreads();   // main-loop reads done before sRed reuse is irrelevant; keeps order
  if (ln15 == 0) {
#pragma unroll
    for (int mt = 0; mt < 2; ++mt)
#pragma unroll
      for (int rg = 0; rg < 4; ++rg)
        sRedA[wc][row0 + mt * 16 + quad * 4 + rg] = rm[mt][rg];
  }
  __syncthreads();

  float gmax[2][4], gsum[2][4];
#pragma unroll
  for (int mt = 0; mt < 2; ++mt)
#pragma unroll
    for (int rg = 0; rg < 4; ++rg) {
      int row = row0 + mt * 16 + quad * 4 + rg;
      float m = sRedA[0][row];
#pragma unroll
      for (int c = 1; c < 8; ++c) m = fmaxf(m, sRedA[c][row]);
      gmax[mt][rg] = m;
      gsum[mt][rg] = 0.f;
    }

#pragma unroll
  for (int nt = 0; nt < 4; ++nt)
#pragma unroll
    for (int mt = 0; mt < 2; ++mt)
#pragma unroll
      for (int rg = 0; rg < 4; ++rg) {
        float e = __expf(acc[mt][nt][rg] - gmax[mt][rg]);
        acc[mt][nt][rg] = e;
        gsum[mt][rg] += e;
      }
#pragma unroll
  for (int mt = 0; mt < 2; ++mt)
#pragma unroll
    for (int rg = 0; rg < 4; ++rg) {
      float v = gsum[mt][rg];
#pragma unroll
      for (int d = 1; d < 16; d <<= 1) v += __shfl_xor(v, d, 64);
      gsum[mt][rg] = v;
    }
  if (ln15 == 0) {
#pragma unroll
    for (int mt = 0; mt < 2; ++mt)
#pragma unroll
      for (int rg = 0; rg < 4; ++rg)
        sRedB[wc][row0 + mt * 16 + quad * 4 + rg] = gsum[mt][rg];
  }
  __syncthreads();
#pragma unroll
  for (int mt = 0; mt < 2; ++mt)
#pragma unroll
    for (int rg = 0; rg < 4; ++rg) {
      int row = row0 + mt * 16 + quad * 4 + rg;
      float s = sRedB[0][row];
#pragma unroll
      for (int c = 1; c < 8; ++c) s += sRedB[c][row];
      gsum[mt][rg] = s;
    }

  float* outBase = attn + ((size_t)batch * NQ + q0) * NK;
#pragma unroll
  for (int mt = 0; mt < 2; ++mt)
#pragma unroll
    for (int rg = 0; rg < 4; ++rg) {
      int row = row0 + mt * 16 + quad * 4 + rg;
      float inv = 1.0f / gsum[mt][rg];
#pragma unroll
      for (int nt = 0; nt < 4; ++nt)
        outBase[(size_t)row * NK + col0 + nt * 16 + ln15] = acc[mt][nt][rg] * inv;
    }

  if (wc == 0 && ln15 == 0) {   // waves 0 (rows 0-31) and 8 (rows 32-63)
    float tv = Tp[0], bv = Bp[0];
#pragma unroll
    for (int mt = 0; mt < 2; ++mt)
#pragma unroll
      for (int rg = 0; rg < 4; ++rg) {
        int row = row0 + mt * 16 + quad * 4 + rg;
        float lse = gmax[mt][rg] + __logf(gsum[mt][rg]);
        float t = (lse + bv) * tv;
        conf[(size_t)batch * NQ + q0 + row] = 1.0f / (1.0f + __expf(-t));
      }
  }
}

// ---------------------------------------------------------------------------
// Fallback: R1 single-kernel path (used only if ws_size < WS_TOTAL)
// ---------------------------------------------------------------------------
__global__ __launch_bounds__(256, 1)
void attn_fused_v1(const float* __restrict__ Qg, const float* __restrict__ Kg,
                   const float* __restrict__ Tp, const float* __restrict__ Bp,
                   float* __restrict__ attn, float* __restrict__ conf) {
  __shared__ __align__(16) unsigned short sAhi[BM1 * BK];
  __shared__ __align__(16) unsigned short sAlo[BM1 * BK];
  __shared__ __align__(16) unsigned short sBhi[NK * BK];
  __shared__ __align__(16) unsigned short sBlo[NK * BK];
  __shared__ float sRedA[4][BM1];
  __shared__ float sRedB[4][BM1];

  const int tid = threadIdx.x;
  const int g = blockIdx.x;
  const int batch = (g & 7) | (((g >> 3) & 3) << 3);
  const int q0 = (g >> 5) * BM1;
  const int ln = tid & 63, w = tid >> 6;
  const int ln15 = ln & 15, quad = ln >> 4;
  const int wn0 = w * 128;

  const float* Qp = Qg + ((size_t)batch * NQ + q0) * ND;
  const float* Kp = Kg + (size_t)batch * NK * ND;

  f32x4 acc[4][8];
#pragma unroll
  for (int mt = 0; mt < 4; ++mt)
#pragma unroll
    for (int nt = 0; nt < 8; ++nt) acc[mt][nt] = (f32x4){0.f, 0.f, 0.f, 0.f};

  float4 pb[16], pa[2];
#pragma unroll
  for (int i = 0; i < 16; ++i) {
    int idx = tid + 256 * i, r = idx >> 3, c4 = idx & 7;
    pb[i] = *(const float4*)(Kp + (size_t)r * ND + c4 * 4);
  }
#pragma unroll
  for (int i = 0; i < 2; ++i) {
    int idx = tid + 256 * i, r = idx >> 3, c4 = idx & 7;
    pa[i] = *(const float4*)(Qp + (size_t)r * ND + c4 * 4);
  }

  for (int kt = 0; kt < NT; ++kt) {
    if (kt) __syncthreads();
#pragma unroll
    for (int i = 0; i < 2; ++i) {
      int idx = tid + 256 * i, r = idx >> 3, c4 = idx & 7;
      int off = lds_off_write(r, c4);
      unsigned h0, h1, h2, h3; float l0, l1, l2, l3;
      bf_split(pa[i].x, h0, l0); bf_split(pa[i].y, h1, l1);
      bf_split(pa[i].z, h2, l2); bf_split(pa[i].w, h3, l3);
      *(uint2*)(&sAhi[off]) = make_uint2((h0 >> 16) | h1, (h2 >> 16) | h3);
      *(uint2*)(&sAlo[off]) = make_uint2(pack_rn(l0, l1), pack_rn(l2, l3));
    }
#pragma unroll
    for (int i = 0; i < 16; ++i) {
      int idx = tid + 256 * i, r = idx >> 3, c4 = idx & 7;
      int off = lds_off_write(r, c4);
      unsigned h0, h1, h2, h3; float l0, l1, l2, l3;
      bf_split(pb[i].x, h0, l0); bf_split(pb[i].y, h1, l1);
      bf_split(pb[i].z, h2, l2); bf_split(pb[i].w, h3, l3);
      *(uint2*)(&sBhi[off]) = make_uint2((h0 >> 16) | h1, (h2 >> 16) | h3);
      *(uint2*)(&sBlo[off]) = make_uint2(pack_rn(l0, l1), pack_rn(l2, l3));
    }
    __syncthreads();

    if (kt < NT - 1) {
      const float* Kq = Kp + (kt + 1) * BK;
      const float* Qq = Qp + (kt + 1) * BK;
#pragma unroll
      for (int i = 0; i < 16; ++i) {
        int idx = tid + 256 * i, r = idx >> 3, c4 = idx & 7;
        pb[i] = *(const float4*)(Kq + (size_t)r * ND + c4 * 4);
      }
#pragma unroll
      for (int i = 0; i < 2; ++i) {
        int idx = tid + 256 * i, r = idx >> 3, c4 = idx & 7;
        pa[i] = *(const float4*)(Qq + (size_t)r * ND + c4 * 4);
      }
    }

    short8 ahi[4], alo[4];
#pragma unroll
    for (int mt = 0; mt < 4; ++mt) {
      int off = lds_off_read(mt * 16 + ln15, quad);
      ahi[mt] = *(const short8*)(&sAhi[off]);
      alo[mt] = *(const short8*)(&sAlo[off]);
    }
#pragma unroll
    for (int nt = 0; nt < 8; ++nt) {
      int off = lds_off_read(wn0 + nt * 16 + ln15, quad);
      short8 bhi = *(const short8*)(&sBhi[off]);
      short8 blo = *(const short8*)(&sBlo[off]);
#pragma unroll
      for (int mt = 0; mt < 4; ++mt) {
        acc[mt][nt] = __builtin_amdgcn_mfma_f32_16x16x32_bf16(ahi[mt], bhi, acc[mt][nt], 0, 0, 0);
        acc[mt][nt] = __builtin_amdgcn_mfma_f32_16x16x32_bf16(ahi[mt], blo, acc[mt][nt], 0, 0, 0);
        acc[mt][nt] = __builtin_amdgcn_mfma_f32_16x16x32_bf16(alo[mt], bhi, acc[mt][nt], 0, 0, 0);
      }
    }
  }

  const float NEGINF = -__builtin_inff();
  float rm[4][4];
#pragma unroll
  for (int mt = 0; mt < 4; ++mt)
#pragma unroll
    for (int rg = 0; rg < 4; ++rg) rm[mt][rg] = NEGINF;
#pragma unroll
  for (int nt = 0; nt < 8; ++nt) {
    int col = wn0 + nt * 16 + ln15;
    bool msk = (Kp[(size_t)col * ND] == 0.0f);
#pragma unroll
    for (int mt = 0; mt < 4; ++mt)
#pragma unroll
      for (int rg = 0; rg < 4; ++rg) {
        float v = msk ? NEGINF : acc[mt][nt][rg];
        acc[mt][nt][rg] = v;
        rm[mt][rg] = fmaxf(rm[mt][rg], v);
      }
  }
#pragma unroll
  for (int mt = 0; mt < 4; ++mt)
#pragma unroll
    for (int rg = 0; rg < 4; ++rg) {
      float v = rm[mt][rg];
#pragma unroll
      for (int d = 1; d < 16; d <<= 1) v = fmaxf(v, __shfl_xor(v, d, 64));
      rm[mt][rg] = v;
    }
  if (ln15 == 0)
#pragma unroll
    for (int mt = 0; mt < 4; ++mt)
#pragma unroll
      for (int rg = 0; rg < 4; ++rg)
        sRedA[w][mt * 16 + quad * 4 + rg] = rm[mt][rg];
  __syncthreads();

  float gmax[4][4], gsum[4][4];
#pragma unroll
  for (int mt = 0; mt < 4; ++mt)
#pragma unroll
    for (int rg = 0; rg < 4; ++rg) {
      int row = mt * 16 + quad * 4 + rg;
      gmax[mt][rg] = fmaxf(fmaxf(sRedA[0][row], sRedA[1][row]),
                           fmaxf(sRedA[2][row], sRedA[3][row]));
      gsum[mt][rg] = 0.f;
    }
#pragma unroll
  for (int nt = 0; nt < 8; ++nt)
#pragma unroll
    for (int mt = 0; mt < 4; ++mt)
#pragma unroll
      for (int rg = 0; rg < 4; ++rg) {
        float e = __expf(acc[mt][nt][rg] - gmax[mt][rg]);
        acc[mt][nt][rg] = e;
        gsum[mt][rg] += e;
      }
#pragma unroll
  for (int mt = 0; mt < 4; ++mt)
#pragma unroll
    for (int rg = 0; rg < 4; ++rg) {
      float v = gsum[mt][rg];
#pragma unroll
      for (int d = 1; d < 16; d <<= 1) v += __shfl_xor(v, d, 64);
      gsum[mt][rg] = v;
    }
  if (ln15 == 0)
#pragma unroll
    for (int mt = 0; mt < 4; ++mt)
#pragma unroll
      for (int rg = 0; rg < 4; ++rg)
        sRedB[w][mt * 16 + quad * 4 + rg] = gsum[mt][rg];
  __syncthreads();
#pragma unroll
  for (int mt = 0; mt < 4; ++mt)
#pragma unroll
    for (int rg = 0; rg < 4; ++rg) {
      int row = mt * 16 + quad * 4 + rg;
      gsum[mt][rg] = sRedB[0][row] + sRedB[1][row] + sRedB[2][row] + sRedB[3][row];
    }

  float* outBase = attn + ((size_t)batch * NQ + q0) * NK;
#pragma unroll
  for (int mt = 0; mt < 4; ++mt)
#pragma unroll
    for (int rg = 0; rg < 4; ++rg) {
      int row = mt * 16 + quad * 4 + rg;
      float inv = 1.0f / gsum[mt][rg];
#pragma unroll
      for (int nt = 0; nt < 8; ++nt)
        outBase[(size_t)row * NK + wn0 + nt * 16 + ln15] = acc[mt][nt][rg] * inv;
    }
  if (w == 0 && ln15 == 0) {
    float tv = Tp[0], bv = Bp[0];
#pragma unroll
    for (int mt = 0; mt < 4; ++mt)
#pragma unroll
      for (int rg = 0; rg < 4; ++rg) {
        int row = mt * 16 + quad * 4 + rg;
        float lse = gmax[mt][rg] + __logf(gsum[mt][rg]);
        float t = (lse + bv) * tv;
        conf[(size_t)batch * NQ + q0 + row] = 1.0f / (1.0f + __expf(-t));
      }
  }
}

extern "C" void kernel_launch(void* const* d_in, const int* in_sizes, int n_in,
                              void* d_out, int out_size, void* d_ws, size_t ws_size,
                              hipStream_t stream) {
  const float* q = (const float*)d_in[0];
  const float* k = (const float*)d_in[1];
  const float* temp = (const float*)d_in[2];
  const float* bias = (const float*)d_in[3];
  float* attn = (float*)d_out;
  float* conf = attn + (size_t)NB * NQ * NK;

  if (ws_size >= WS_TOTAL) {
    hipLaunchKernelGGL(convert_k, dim3(NB * NT), dim3(256), 0, stream,
                       k, (unsigned char*)d_ws);
    hipLaunchKernelGGL(attn_fused_v3, dim3(NB * (NQ / BM3)), dim3(1024), 0, stream,
                       q, (const unsigned char*)d_ws, temp, bias, attn, conf);
  } else {
    hipLaunchKernelGGL(attn_fused_v1, dim3(NB * (NQ / BM1)), dim3(256), 0, stream,
                       q, k, temp, bias, attn, conf);
  }
}